// Round 8
// baseline (152.745 us; speedup 1.0000x reference)
//
#include <hip/hip_runtime.h>
#include <stdint.h>

#define QCNT 256
#define NKEYS 10000
#define DDIM 128
#define KSEL 10
#define OBSROW 28224  // 4*84*84
#define QPW 4         // queries per wave (block = 1 wave)
#define CHUNK 512     // keys per block chunk
#define NCHUNK ((NKEYS + CHUNK - 1) / CHUNK)  // 20
#define NTILE 8       // lane owns 8 keys (8 x 64 = 512)
#define SEGF4 4       // float4 per q/k segment (16 floats)
#define NSEG 8        // 8 segs x 16 floats = 128
#define NCAND (NCHUNK * KSEL)  // 200 candidates per query

typedef float f4v __attribute__((ext_vector_type(4)));

// Monotone (dist, idx) -> u64 encoding; dist = kk - 2*dot can be negative
// (q2 constant dropped); sign-flip trick keeps total order.
__device__ inline unsigned long long enc_key(float d, int n) {
  unsigned u = __float_as_uint(d);
  u ^= (unsigned)((int)u >> 31) | 0x80000000u;
  return ((unsigned long long)u << 32) | (unsigned)n;
}

__device__ inline unsigned long long wave_min_u64(unsigned long long w) {
#pragma unroll
  for (int off = 1; off < 64; off <<= 1) {
    unsigned long long o =
        (unsigned long long)__shfl_xor((long long)w, off, 64);
    if (o < w) w = o;
  }
  return w;
}

// ---------------------------------------------------------------------------
// Kernel 1 (R8): ZERO-LDS, ZERO-BARRIER part kernel. Block = 1 wave.
// Lane owns 8 keys; wave owns 4 queries x 512-key chunk. Per (seg, key):
// 4x global_load_dwordx4 of the lane's OWN key row slice (consecutive 16 B
// -> 4x L1 line reuse) + 80 FMAs. No __syncthreads anywhere: the compiler
// pipelines loads across key-steps with counted vmcnt. q segment (4 q x 16
// floats = 64 VGPR) via wave-uniform s_load, refreshed once per seg.
// ---------------------------------------------------------------------------
__global__ __launch_bounds__(64) void knn_part_kernel(
    const float* __restrict__ q, const float* __restrict__ k,
    unsigned long long* __restrict__ part) {
  const int qg   = blockIdx.x;  // 0..63 (4-query group)
  const int ch   = blockIdx.y;  // 0..19
  const int lane = threadIdx.x; // 0..63

  const int kbase = ch * CHUNK;
  const int kend  = (kbase + CHUNK < NKEYS) ? kbase + CHUNK : NKEYS;
  const int q0    = qg * QPW;

  // Accumulators: 4 dots x 8 keys + 8 kk = 40 VGPR. Static indices only.
  float dot[QPW][NTILE];
  float kk[NTILE];
#pragma unroll
  for (int t = 0; t < NTILE; ++t) {
    kk[t] = 0.f;
#pragma unroll
    for (int qi = 0; qi < QPW; ++qi) dot[qi][t] = 0.f;
  }

#pragma unroll 1
  for (int seg = 0; seg < NSEG; ++seg) {
    // q segment -> registers (wave-uniform address -> scalar loads).
    f4v qs[QPW][SEGF4];
#pragma unroll
    for (int qi = 0; qi < QPW; ++qi) {
#pragma unroll
      for (int jj = 0; jj < SEGF4; ++jj) {
        qs[qi][jj] =
            ((const f4v*)(q + (size_t)(q0 + qi) * DDIM))[seg * SEGF4 + jj];
      }
    }

#pragma unroll 2
    for (int t = 0; t < NTILE; ++t) {
      const int n  = kbase + t * 64 + lane;
      const int nc = (n < NKEYS) ? n : (NKEYS - 1);  // clamped safe load
      const f4v* kr = (const f4v*)(k + (size_t)nc * DDIM) + seg * SEGF4;
      f4v kv[SEGF4];
#pragma unroll
      for (int jj = 0; jj < SEGF4; ++jj) kv[jj] = kr[jj];

      float c = kk[t];
#pragma unroll
      for (int jj = 0; jj < SEGF4; ++jj) {
        c = fmaf(kv[jj].x, kv[jj].x, c);
        c = fmaf(kv[jj].y, kv[jj].y, c);
        c = fmaf(kv[jj].z, kv[jj].z, c);
        c = fmaf(kv[jj].w, kv[jj].w, c);
      }
      kk[t] = c;
#pragma unroll
      for (int qi = 0; qi < QPW; ++qi) {
        float a = dot[qi][t];
#pragma unroll
        for (int jj = 0; jj < SEGF4; ++jj) {
          a = fmaf(kv[jj].x, qs[qi][jj].x, a);
          a = fmaf(kv[jj].y, qs[qi][jj].y, a);
          a = fmaf(kv[jj].z, qs[qi][jj].z, a);
          a = fmaf(kv[jj].w, qs[qi][jj].w, a);
        }
        dot[qi][t] = a;
      }
    }
  }

  // Extraction, one query at a time (keeps register pressure low).
  // Lane's 8 candidates in regs; 10 rounds of {min-of-8, wave-min,
  // tombstone}. All array indices static via full unrolls.
#pragma unroll 1
  for (int qi = 0; qi < QPW; ++qi) {
    unsigned long long cand[NTILE];
#pragma unroll
    for (int t = 0; t < NTILE; ++t) {
      const int n = kbase + t * 64 + lane;
      cand[t] = (n < kend) ? enc_key(fmaf(-2.f, dot[qi][t], kk[t]), n)
                           : ~0ULL;
    }
    unsigned long long* dst =
        part + ((size_t)(q0 + qi) * NCHUNK + ch) * KSEL;
#pragma unroll 1
    for (int r = 0; r < KSEL; ++r) {
      unsigned long long m = cand[0];
#pragma unroll
      for (int t = 1; t < NTILE; ++t) m = (cand[t] < m) ? cand[t] : m;
      const unsigned long long w = wave_min_u64(m);
#pragma unroll
      for (int t = 0; t < NTILE; ++t) {
        if (cand[t] == w) cand[t] = ~0ULL;
      }
      if (lane == 0) dst[r] = w;
    }
  }
}

// ---------------------------------------------------------------------------
// Kernel 2: fused merge + gather. UNCHANGED from R5 (cached loads + NT
// stores, barrier-free redundant per-wave merge, scalar copy base).
// ---------------------------------------------------------------------------
__global__ __launch_bounds__(256) void knn_merge_gather_kernel(
    const float* __restrict__ obs, const unsigned long long* __restrict__ part,
    float* __restrict__ out) {
  const int b    = blockIdx.x;  // b = r*QCNT + q
  const int r    = b >> 8;      // QCNT == 256
  const int qq   = b & 255;
  const int tid  = threadIdx.x;
  const int lane = tid & 63;

  const unsigned long long* cp = part + (size_t)qq * NCAND;
  unsigned long long c0 = cp[lane];
  unsigned long long c1 = cp[lane + 64];
  unsigned long long c2 = cp[lane + 128];
  unsigned long long c3 = (lane + 192 < NCAND) ? cp[lane + 192] : ~0ULL;
  unsigned long long w = ~0ULL;
#pragma unroll 1
  for (int round = 0; round <= r; ++round) {
    unsigned long long m = c0;
    m = (c1 < m) ? c1 : m;
    m = (c2 < m) ? c2 : m;
    m = (c3 < m) ? c3 : m;
    w = wave_min_u64(m);
    if (c0 == w) c0 = ~0ULL;
    if (c1 == w) c1 = ~0ULL;
    if (c2 == w) c2 = ~0ULL;
    if (c3 == w) c3 = ~0ULL;
  }
  // wave-uniform -> force into SGPR so the copy base is scalar
  const int src = __builtin_amdgcn_readfirstlane((int)(w & 0xffffffffu));

  const f4v* __restrict__ s = (const f4v*)(obs + (size_t)src * OBSROW);
  f4v* __restrict__ d       = (f4v*)(out + (size_t)b * OBSROW);
#pragma unroll 4
  for (int i = tid; i < OBSROW / 4; i += 256) {
    f4v v = s[i];  // cached load: L3 catches duplicate rows
    __builtin_nontemporal_store(v, &d[i]);
  }
}

extern "C" void kernel_launch(void* const* d_in, const int* in_sizes, int n_in,
                              void* d_out, int out_size, void* d_ws,
                              size_t ws_size, hipStream_t stream) {
  const float* q   = (const float*)d_in[0];  // [256,128]
  const float* k   = (const float*)d_in[1];  // [10000,128]
  const float* obs = (const float*)d_in[2];  // [10000,4,84,84]
  float* out = (float*)d_out;                // [10,256,4,84,84]

  unsigned long long* part = (unsigned long long*)d_ws;  // 409600 B

  knn_part_kernel<<<dim3(QCNT / QPW, NCHUNK), 64, 0, stream>>>(q, k, part);
  knn_merge_gather_kernel<<<KSEL * QCNT, 256, 0, stream>>>(obs, part, out);
}

// Round 9
// 148.214 us; speedup vs baseline: 1.0306x; 1.0306x over previous
//
#include <hip/hip_runtime.h>
#include <stdint.h>

#define QCNT 256
#define NKEYS 10000
#define DDIM 128
#define KSEL 10
#define OBSROW 28224  // 4*84*84
#define QPW 4         // queries per wave (block = 1 wave)
#define SEGF4 4       // float4 per q/k segment (16 floats)
#define NSEG 8        // 8 segs x 16 floats = 128

typedef float f4v __attribute__((ext_vector_type(4)));

// Monotone (dist, idx) -> u64 encoding; dist = kk - 2*dot can be negative
// (q2 constant dropped); sign-flip trick keeps total order.
__device__ inline unsigned long long enc_key(float d, int n) {
  unsigned u = __float_as_uint(d);
  u ^= (unsigned)((int)u >> 31) | 0x80000000u;
  return ((unsigned long long)u << 32) | (unsigned)n;
}

__device__ inline unsigned long long wave_min_u64(unsigned long long w) {
#pragma unroll
  for (int off = 1; off < 64; off <<= 1) {
    unsigned long long o =
        (unsigned long long)__shfl_xor((long long)w, off, 64);
    if (o < w) w = o;
  }
  return w;
}

// ---------------------------------------------------------------------------
// Kernel 1: zero-LDS, zero-barrier part kernel (R8 structure), templated on
// CHUNK so the occupancy can be set by the host. CHUNK=256 -> 2560 single-
// wave blocks = 2.5 waves/SIMD (R8's 512 gave only 1.25 -> latency-starved).
// Lane owns CHUNK/64 keys x 4 queries; loads its OWN key row slice directly
// from global (L1/L2-resident), compiler pipelines with counted vmcnt.
// ---------------------------------------------------------------------------
template <int CHUNK_T>
__global__ __launch_bounds__(64) void knn_part_kernel(
    const float* __restrict__ q, const float* __restrict__ k,
    unsigned long long* __restrict__ part) {
  constexpr int NCHUNK_T = (NKEYS + CHUNK_T - 1) / CHUNK_T;
  constexpr int NTILE_T  = CHUNK_T / 64;

  const int qg   = blockIdx.x;
  const int ch   = blockIdx.y;
  const int lane = threadIdx.x;  // 0..63

  const int kbase = ch * CHUNK_T;
  const int kend  = (kbase + CHUNK_T < NKEYS) ? kbase + CHUNK_T : NKEYS;
  const int q0    = qg * QPW;

  float dot[QPW][NTILE_T];
  float kk[NTILE_T];
#pragma unroll
  for (int t = 0; t < NTILE_T; ++t) {
    kk[t] = 0.f;
#pragma unroll
    for (int qi = 0; qi < QPW; ++qi) dot[qi][t] = 0.f;
  }

#pragma unroll 1
  for (int seg = 0; seg < NSEG; ++seg) {
    // q segment -> registers (wave-uniform address -> scalar loads).
    f4v qs[QPW][SEGF4];
#pragma unroll
    for (int qi = 0; qi < QPW; ++qi) {
#pragma unroll
      for (int jj = 0; jj < SEGF4; ++jj) {
        qs[qi][jj] =
            ((const f4v*)(q + (size_t)(q0 + qi) * DDIM))[seg * SEGF4 + jj];
      }
    }

#pragma unroll 2
    for (int t = 0; t < NTILE_T; ++t) {
      const int n  = kbase + t * 64 + lane;
      const int nc = (n < NKEYS) ? n : (NKEYS - 1);  // clamped safe load
      const f4v* kr = (const f4v*)(k + (size_t)nc * DDIM) + seg * SEGF4;
      f4v kv[SEGF4];
#pragma unroll
      for (int jj = 0; jj < SEGF4; ++jj) kv[jj] = kr[jj];

      float c = kk[t];
#pragma unroll
      for (int jj = 0; jj < SEGF4; ++jj) {
        c = fmaf(kv[jj].x, kv[jj].x, c);
        c = fmaf(kv[jj].y, kv[jj].y, c);
        c = fmaf(kv[jj].z, kv[jj].z, c);
        c = fmaf(kv[jj].w, kv[jj].w, c);
      }
      kk[t] = c;
#pragma unroll
      for (int qi = 0; qi < QPW; ++qi) {
        float a = dot[qi][t];
#pragma unroll
        for (int jj = 0; jj < SEGF4; ++jj) {
          a = fmaf(kv[jj].x, qs[qi][jj].x, a);
          a = fmaf(kv[jj].y, qs[qi][jj].y, a);
          a = fmaf(kv[jj].z, qs[qi][jj].z, a);
          a = fmaf(kv[jj].w, qs[qi][jj].w, a);
        }
        dot[qi][t] = a;
      }
    }
  }

  // Exact selection: 10 rounds of {min over owned cands, wave-min,
  // tombstone} per query. All indices static (full unrolls).
#pragma unroll 1
  for (int qi = 0; qi < QPW; ++qi) {
    unsigned long long cand[NTILE_T];
#pragma unroll
    for (int t = 0; t < NTILE_T; ++t) {
      const int n = kbase + t * 64 + lane;
      cand[t] = (n < kend) ? enc_key(fmaf(-2.f, dot[qi][t], kk[t]), n)
                           : ~0ULL;
    }
    unsigned long long* dst =
        part + ((size_t)(q0 + qi) * NCHUNK_T + ch) * KSEL;
#pragma unroll 1
    for (int r = 0; r < KSEL; ++r) {
      unsigned long long m = cand[0];
#pragma unroll
      for (int t = 1; t < NTILE_T; ++t) m = (cand[t] < m) ? cand[t] : m;
      const unsigned long long w = wave_min_u64(m);
#pragma unroll
      for (int t = 0; t < NTILE_T; ++t) {
        if (cand[t] == w) cand[t] = ~0ULL;
      }
      if (lane == 0) dst[r] = w;
    }
  }
}

// ---------------------------------------------------------------------------
// Kernel 2: fused merge + gather (R5-proven copy: cached loads + NT stores,
// barrier-free redundant per-wave merge, scalar copy base). Templated on
// NCHUNK; candidate slots = ceil(NCHUNK*KSEL/64), all statically indexed.
// ---------------------------------------------------------------------------
template <int NCHUNK_T>
__global__ __launch_bounds__(256) void knn_merge_gather_kernel(
    const float* __restrict__ obs, const unsigned long long* __restrict__ part,
    float* __restrict__ out) {
  constexpr int NCAND_T = NCHUNK_T * KSEL;
  constexpr int SLOTS   = (NCAND_T + 63) / 64;

  const int b    = blockIdx.x;  // b = r*QCNT + q
  const int r    = b >> 8;      // QCNT == 256
  const int qq   = b & 255;
  const int tid  = threadIdx.x;
  const int lane = tid & 63;

  const unsigned long long* cp = part + (size_t)qq * NCAND_T;
  unsigned long long c[SLOTS];
#pragma unroll
  for (int i = 0; i < SLOTS; ++i) {
    const int idx = lane + 64 * i;
    c[i] = (idx < NCAND_T) ? cp[idx] : ~0ULL;
  }
  unsigned long long w = ~0ULL;
#pragma unroll 1
  for (int round = 0; round <= r; ++round) {
    unsigned long long m = c[0];
#pragma unroll
    for (int i = 1; i < SLOTS; ++i) m = (c[i] < m) ? c[i] : m;
    w = wave_min_u64(m);
#pragma unroll
    for (int i = 0; i < SLOTS; ++i) {
      if (c[i] == w) c[i] = ~0ULL;
    }
  }
  // wave-uniform -> force into SGPR so the copy base is scalar
  const int src = __builtin_amdgcn_readfirstlane((int)(w & 0xffffffffu));

  const f4v* __restrict__ s = (const f4v*)(obs + (size_t)src * OBSROW);
  f4v* __restrict__ d       = (f4v*)(out + (size_t)b * OBSROW);
#pragma unroll 4
  for (int i = tid; i < OBSROW / 4; i += 256) {
    f4v v = s[i];  // cached load: L3 catches duplicate rows
    __builtin_nontemporal_store(v, &d[i]);
  }
}

extern "C" void kernel_launch(void* const* d_in, const int* in_sizes, int n_in,
                              void* d_out, int out_size, void* d_ws,
                              size_t ws_size, hipStream_t stream) {
  const float* q   = (const float*)d_in[0];  // [256,128]
  const float* k   = (const float*)d_in[1];  // [10000,128]
  const float* obs = (const float*)d_in[2];  // [10000,4,84,84]
  float* out = (float*)d_out;                // [10,256,4,84,84]

  unsigned long long* part = (unsigned long long*)d_ws;

  // Preferred: CHUNK=256 -> 2560 waves (2.5/SIMD), part buffer 819200 B.
  // Fallback if scratch is tight: CHUNK=512 (R8 layout, 409600 B).
  constexpr int NCHUNK_A = (NKEYS + 255) / 256;  // 40
  constexpr int NCHUNK_B = (NKEYS + 511) / 512;  // 20
  const size_t needA = (size_t)QCNT * NCHUNK_A * KSEL * 8;  // 819200

  if (ws_size >= needA) {
    knn_part_kernel<256>
        <<<dim3(QCNT / QPW, NCHUNK_A), 64, 0, stream>>>(q, k, part);
    knn_merge_gather_kernel<NCHUNK_A>
        <<<KSEL * QCNT, 256, 0, stream>>>(obs, part, out);
  } else {
    knn_part_kernel<512>
        <<<dim3(QCNT / QPW, NCHUNK_B), 64, 0, stream>>>(q, k, part);
    knn_merge_gather_kernel<NCHUNK_B>
        <<<KSEL * QCNT, 256, 0, stream>>>(obs, part, out);
  }
}

// Round 10
// 131.586 us; speedup vs baseline: 1.1608x; 1.1264x over previous
//
#include <hip/hip_runtime.h>
#include <stdint.h>

#define QCNT 256
#define NKEYS 10000
#define DDIM 128
#define KSEL 10
#define OBSROW 28224  // 4*84*84

typedef float f4v __attribute__((ext_vector_type(4)));
typedef float f32x4 __attribute__((ext_vector_type(4)));
typedef _Float16 f16x8 __attribute__((ext_vector_type(8)));
typedef _Float16 f16x4 __attribute__((ext_vector_type(4)));

// ---------------- MFMA path geometry ----------------
#define QTILE 16                      // queries per block (MFMA N)
#define KCHUNK 80                     // keys per chunk: 125*80 = 10000 exact
#define NTILES 5                      // 16-key tiles per chunk
#define NCHUNK_M (NKEYS / KCHUNK)     // 125
#define NCAND_M (NCHUNK_M * KSEL)     // 1250
#define LISTM 10

// ws layout (bytes)
#define WS_PART 0
#define SZ_PART (QCNT * NCHUNK_M * KSEL * 8)          // 2,560,000
#define WS_K2 (WS_PART + SZ_PART)
#define SZ_K2 40960
#define WS_KHI (WS_K2 + SZ_K2)
#define SZ_KF16 (NKEYS * DDIM * 2)                    // 2,560,000
#define WS_KLO (WS_KHI + SZ_KF16)
#define WS_QHI (WS_KLO + SZ_KF16)
#define SZ_QF16 (QCNT * DDIM * 2)                     // 65,536
#define WS_QLO (WS_QHI + SZ_QF16)
#define WS_TOTAL (WS_QLO + SZ_QF16)                   // 7,852,032

// Monotone (dist, idx) -> u64; dist may be negative (q2 dropped).
__device__ inline unsigned long long enc_key(float d, int n) {
  unsigned u = __float_as_uint(d);
  u ^= (unsigned)((int)u >> 31) | 0x80000000u;
  return ((unsigned long long)u << 32) | (unsigned)n;
}

__device__ inline unsigned long long wave_min_u64(unsigned long long w) {
#pragma unroll
  for (int off = 1; off < 64; off <<= 1) {
    unsigned long long o =
        (unsigned long long)__shfl_xor((long long)w, off, 64);
    if (o < w) w = o;
  }
  return w;
}

__device__ inline void insert10(unsigned long long best[LISTM],
                                unsigned long long key) {
  if (key < best[LISTM - 1]) {
    best[LISTM - 1] = key;
#pragma unroll
    for (int s = LISTM - 1; s >= 1; --s) {
      if (best[s] < best[s - 1]) {
        unsigned long long t = best[s];
        best[s] = best[s - 1];
        best[s - 1] = t;
      }
    }
  }
}

// ---------------------------------------------------------------------------
// Pre-kernel A: fp32 -> (hi, lo) fp16 planes. 4 elems/thread.
// ---------------------------------------------------------------------------
__global__ __launch_bounds__(256) void convert_hilo_kernel(
    const float* __restrict__ src, _Float16* __restrict__ hi,
    _Float16* __restrict__ lo, int n) {
  int i = (blockIdx.x * 256 + threadIdx.x) * 4;
  if (i >= n) return;
  float4 v = *(const float4*)(src + i);
  _Float16 h0 = (_Float16)v.x, h1 = (_Float16)v.y;
  _Float16 h2 = (_Float16)v.z, h3 = (_Float16)v.w;
  f16x4 hv = {h0, h1, h2, h3};
  f16x4 lv = {(_Float16)(v.x - (float)h0), (_Float16)(v.y - (float)h1),
              (_Float16)(v.z - (float)h2), (_Float16)(v.w - (float)h3)};
  *(f16x4*)(hi + i) = hv;
  *(f16x4*)(lo + i) = lv;
}

// ---------------------------------------------------------------------------
// Pre-kernel B: k2[n] = ||k_n||^2 in exact fp32 (from original fp32 k).
// ---------------------------------------------------------------------------
__global__ __launch_bounds__(256) void k2_kernel(const float* __restrict__ k,
                                                 float* __restrict__ k2) {
  int n = blockIdx.x * 256 + threadIdx.x;
  if (n >= NKEYS) return;
  const float4* row = (const float4*)(k + (size_t)n * DDIM);
  float s = 0.f;
#pragma unroll
  for (int j = 0; j < DDIM / 4; ++j) {
    float4 v = row[j];
    s += v.x * v.x + v.y * v.y + v.z * v.z + v.w * v.w;
  }
  k2[n] = s;
}

// ---------------------------------------------------------------------------
// Kernel 1 (MFMA): one wave per (16-query tile, 80-key chunk).
// Split-fp16 3-MFMA dot: d = k2 - 2*(Ah*Bh + Ah*Bl + Al*Bh); ll-term
// dropped (<1e-4). A = keys (M), B = queries (N), 16x16x32_f16:
//   A: row=lane&15, k=(lane>>4)*8+j   B: col=lane&15, k=(lane>>4)*8+j
//   D: col=lane&15 (query), row=(lane>>4)*4+reg (key)   [m89 layout]
// Each lane owns 4 keys x its query per tile -> sorted top-10 list ->
// 4-lane (xor 16,32) tombstone merge -> per-chunk top-10 to part.
// No LDS, no barriers. 2000 single-wave blocks.
// ---------------------------------------------------------------------------
__global__ __launch_bounds__(64) void knn_part_mfma(
    const _Float16* __restrict__ khi, const _Float16* __restrict__ klo,
    const _Float16* __restrict__ qhi, const _Float16* __restrict__ qlo,
    const float* __restrict__ k2g, unsigned long long* __restrict__ part) {
  const int qt   = blockIdx.x;   // 0..15
  const int ch   = blockIdx.y;   // 0..124
  const int lane = threadIdx.x;  // 0..63
  const int lq   = lane & 15;
  const int lk8  = (lane >> 4) * 8;

  const int q0 = qt * QTILE;
  // B fragments (queries) once per block: 4 K-chunks x {hi,lo}.
  f16x8 bh[4], bl[4];
  {
    const _Float16* qb_h = qhi + (size_t)(q0 + lq) * DDIM + lk8;
    const _Float16* qb_l = qlo + (size_t)(q0 + lq) * DDIM + lk8;
#pragma unroll
    for (int kc = 0; kc < 4; ++kc) {
      bh[kc] = *(const f16x8*)(qb_h + kc * 32);
      bl[kc] = *(const f16x8*)(qb_l + kc * 32);
    }
  }

  unsigned long long list[LISTM];
#pragma unroll
  for (int s = 0; s < LISTM; ++s) list[s] = ~0ULL;

  const int kbase = ch * KCHUNK;
#pragma unroll
  for (int t = 0; t < NTILES; ++t) {
    const int tb = kbase + t * 16;          // tile base key (always <10000)
    const _Float16* ah_p = khi + (size_t)(tb + lq) * DDIM + lk8;
    const _Float16* al_p = klo + (size_t)(tb + lq) * DDIM + lk8;

    f32x4 acc = {0.f, 0.f, 0.f, 0.f};
#pragma unroll
    for (int kc = 0; kc < 4; ++kc) {
      f16x8 ah = *(const f16x8*)(ah_p + kc * 32);
      f16x8 al = *(const f16x8*)(al_p + kc * 32);
      acc = __builtin_amdgcn_mfma_f32_16x16x32_f16(ah, bh[kc], acc, 0, 0, 0);
      acc = __builtin_amdgcn_mfma_f32_16x16x32_f16(ah, bl[kc], acc, 0, 0, 0);
      acc = __builtin_amdgcn_mfma_f32_16x16x32_f16(al, bh[kc], acc, 0, 0, 0);
    }

    const int r0 = tb + (lane >> 4) * 4;    // this lane's first key row
    f32x4 k2v = *(const f32x4*)(k2g + r0);  // 16B aligned (r0 % 4 == 0)
#pragma unroll
    for (int reg = 0; reg < 4; ++reg) {
      insert10(list, enc_key(fmaf(-2.f, acc[reg], k2v[reg]), r0 + reg));
    }
  }

  // Tombstone-extract top-10 across the 4 lanes sharing query lq.
  unsigned long long* dst =
      part + ((size_t)(q0 + lq) * NCHUNK_M + ch) * KSEL;
#pragma unroll 1
  for (int r = 0; r < KSEL; ++r) {
    unsigned long long w = list[0];
    {
      unsigned long long o =
          (unsigned long long)__shfl_xor((long long)w, 16, 64);
      if (o < w) w = o;
      o = (unsigned long long)__shfl_xor((long long)w, 32, 64);
      if (o < w) w = o;
    }
    if (list[0] == w) {
#pragma unroll
      for (int s = 0; s < LISTM - 1; ++s) list[s] = list[s + 1];
      list[LISTM - 1] = ~0ULL;
    }
    if (lane < 16) dst[r] = w;
  }
}

// ---------------------------------------------------------------------------
// Fallback scalar part kernel (R9-proven), used only if ws is too small.
// ---------------------------------------------------------------------------
#define QPW 4
#define SEGF4 4
#define NSEG 8
template <int CHUNK_T>
__global__ __launch_bounds__(64) void knn_part_scalar(
    const float* __restrict__ q, const float* __restrict__ k,
    unsigned long long* __restrict__ part) {
  constexpr int NCHUNK_T = (NKEYS + CHUNK_T - 1) / CHUNK_T;
  constexpr int NTILE_T  = CHUNK_T / 64;
  const int qg = blockIdx.x, ch = blockIdx.y, lane = threadIdx.x;
  const int kbase = ch * CHUNK_T;
  const int kend  = (kbase + CHUNK_T < NKEYS) ? kbase + CHUNK_T : NKEYS;
  const int q0    = qg * QPW;
  float dot[QPW][NTILE_T], kk[NTILE_T];
#pragma unroll
  for (int t = 0; t < NTILE_T; ++t) {
    kk[t] = 0.f;
#pragma unroll
    for (int qi = 0; qi < QPW; ++qi) dot[qi][t] = 0.f;
  }
#pragma unroll 1
  for (int seg = 0; seg < NSEG; ++seg) {
    f4v qs[QPW][SEGF4];
#pragma unroll
    for (int qi = 0; qi < QPW; ++qi)
#pragma unroll
      for (int jj = 0; jj < SEGF4; ++jj)
        qs[qi][jj] =
            ((const f4v*)(q + (size_t)(q0 + qi) * DDIM))[seg * SEGF4 + jj];
#pragma unroll 2
    for (int t = 0; t < NTILE_T; ++t) {
      const int n  = kbase + t * 64 + lane;
      const int nc = (n < NKEYS) ? n : (NKEYS - 1);
      const f4v* kr = (const f4v*)(k + (size_t)nc * DDIM) + seg * SEGF4;
      f4v kv[SEGF4];
#pragma unroll
      for (int jj = 0; jj < SEGF4; ++jj) kv[jj] = kr[jj];
      float c = kk[t];
#pragma unroll
      for (int jj = 0; jj < SEGF4; ++jj) {
        c = fmaf(kv[jj].x, kv[jj].x, c);
        c = fmaf(kv[jj].y, kv[jj].y, c);
        c = fmaf(kv[jj].z, kv[jj].z, c);
        c = fmaf(kv[jj].w, kv[jj].w, c);
      }
      kk[t] = c;
#pragma unroll
      for (int qi = 0; qi < QPW; ++qi) {
        float a = dot[qi][t];
#pragma unroll
        for (int jj = 0; jj < SEGF4; ++jj) {
          a = fmaf(kv[jj].x, qs[qi][jj].x, a);
          a = fmaf(kv[jj].y, qs[qi][jj].y, a);
          a = fmaf(kv[jj].z, qs[qi][jj].z, a);
          a = fmaf(kv[jj].w, qs[qi][jj].w, a);
        }
        dot[qi][t] = a;
      }
    }
  }
#pragma unroll 1
  for (int qi = 0; qi < QPW; ++qi) {
    unsigned long long cand[NTILE_T];
#pragma unroll
    for (int t = 0; t < NTILE_T; ++t) {
      const int n = kbase + t * 64 + lane;
      cand[t] = (n < kend) ? enc_key(fmaf(-2.f, dot[qi][t], kk[t]), n)
                           : ~0ULL;
    }
    unsigned long long* dst =
        part + ((size_t)(q0 + qi) * NCHUNK_T + ch) * KSEL;
#pragma unroll 1
    for (int r = 0; r < KSEL; ++r) {
      unsigned long long m = cand[0];
#pragma unroll
      for (int t = 1; t < NTILE_T; ++t) m = (cand[t] < m) ? cand[t] : m;
      const unsigned long long w = wave_min_u64(m);
#pragma unroll
      for (int t = 0; t < NTILE_T; ++t)
        if (cand[t] == w) cand[t] = ~0ULL;
      if (lane == 0) dst[r] = w;
    }
  }
}

// ---------------------------------------------------------------------------
// Kernel 2: fused merge + gather (R5-proven: cached loads + NT stores,
// barrier-free redundant per-wave merge, scalar copy base).
// ---------------------------------------------------------------------------
template <int NCHUNK_T>
__global__ __launch_bounds__(256) void knn_merge_gather_kernel(
    const float* __restrict__ obs, const unsigned long long* __restrict__ part,
    float* __restrict__ out) {
  constexpr int NCAND_T = NCHUNK_T * KSEL;
  constexpr int SLOTS   = (NCAND_T + 63) / 64;

  const int b    = blockIdx.x;  // b = r*QCNT + q
  const int r    = b >> 8;
  const int qq   = b & 255;
  const int tid  = threadIdx.x;
  const int lane = tid & 63;

  const unsigned long long* cp = part + (size_t)qq * NCAND_T;
  unsigned long long c[SLOTS];
#pragma unroll
  for (int i = 0; i < SLOTS; ++i) {
    const int idx = lane + 64 * i;
    c[i] = (idx < NCAND_T) ? cp[idx] : ~0ULL;
  }
  unsigned long long w = ~0ULL;
#pragma unroll 1
  for (int round = 0; round <= r; ++round) {
    unsigned long long m = c[0];
#pragma unroll
    for (int i = 1; i < SLOTS; ++i) m = (c[i] < m) ? c[i] : m;
    w = wave_min_u64(m);
#pragma unroll
    for (int i = 0; i < SLOTS; ++i)
      if (c[i] == w) c[i] = ~0ULL;
  }
  const int src = __builtin_amdgcn_readfirstlane((int)(w & 0xffffffffu));

  const f4v* __restrict__ s = (const f4v*)(obs + (size_t)src * OBSROW);
  f4v* __restrict__ d       = (f4v*)(out + (size_t)b * OBSROW);
#pragma unroll 4
  for (int i = tid; i < OBSROW / 4; i += 256) {
    f4v v = s[i];
    __builtin_nontemporal_store(v, &d[i]);
  }
}

extern "C" void kernel_launch(void* const* d_in, const int* in_sizes, int n_in,
                              void* d_out, int out_size, void* d_ws,
                              size_t ws_size, hipStream_t stream) {
  const float* q   = (const float*)d_in[0];  // [256,128]
  const float* k   = (const float*)d_in[1];  // [10000,128]
  const float* obs = (const float*)d_in[2];  // [10000,4,84,84]
  float* out = (float*)d_out;                // [10,256,4,84,84]
  char* ws = (char*)d_ws;

  if (ws_size >= (size_t)WS_TOTAL) {
    unsigned long long* part = (unsigned long long*)(ws + WS_PART);
    float* k2       = (float*)(ws + WS_K2);
    _Float16* khi   = (_Float16*)(ws + WS_KHI);
    _Float16* klo   = (_Float16*)(ws + WS_KLO);
    _Float16* qhi   = (_Float16*)(ws + WS_QHI);
    _Float16* qlo   = (_Float16*)(ws + WS_QLO);

    const int nk = NKEYS * DDIM;   // 1,280,000
    const int nq = QCNT * DDIM;    // 32,768
    convert_hilo_kernel<<<(nk / 4 + 255) / 256, 256, 0, stream>>>(k, khi, klo,
                                                                  nk);
    convert_hilo_kernel<<<(nq / 4 + 255) / 256, 256, 0, stream>>>(q, qhi, qlo,
                                                                  nq);
    k2_kernel<<<(NKEYS + 255) / 256, 256, 0, stream>>>(k, k2);
    knn_part_mfma<<<dim3(QCNT / QTILE, NCHUNK_M), 64, 0, stream>>>(
        khi, klo, qhi, qlo, k2, part);
    knn_merge_gather_kernel<NCHUNK_M>
        <<<KSEL * QCNT, 256, 0, stream>>>(obs, part, out);
  } else {
    // Fallback: R9 scalar engine (needs only 819,200 B).
    unsigned long long* part = (unsigned long long*)ws;
    constexpr int NCHUNK_A = (NKEYS + 255) / 256;  // 40
    constexpr int NCHUNK_B = (NKEYS + 511) / 512;  // 20
    const size_t needA = (size_t)QCNT * NCHUNK_A * KSEL * 8;
    if (ws_size >= needA) {
      knn_part_scalar<256>
          <<<dim3(QCNT / QPW, NCHUNK_A), 64, 0, stream>>>(q, k, part);
      knn_merge_gather_kernel<NCHUNK_A>
          <<<KSEL * QCNT, 256, 0, stream>>>(obs, part, out);
    } else {
      knn_part_scalar<512>
          <<<dim3(QCNT / QPW, NCHUNK_B), 64, 0, stream>>>(q, k, part);
      knn_merge_gather_kernel<NCHUNK_B>
          <<<KSEL * QCNT, 256, 0, stream>>>(obs, part, out);
    }
  }
}

// Round 11
// 118.313 us; speedup vs baseline: 1.2910x; 1.1122x over previous
//
#include <hip/hip_runtime.h>
#include <stdint.h>

#define QCNT 256
#define NKEYS 10000
#define DDIM 128
#define KSEL 10
#define OBSROW 28224  // 4*84*84

typedef float f4v __attribute__((ext_vector_type(4)));
typedef float f32x4 __attribute__((ext_vector_type(4)));
typedef _Float16 f16x8 __attribute__((ext_vector_type(8)));

// ---------------- MFMA path geometry ----------------
#define QTILE 16                   // queries per block (MFMA N)
#define KCHUNK 80                  // keys per chunk: 125*80 = 10000 exact
#define NTILES 5                   // 16-key tiles per chunk
#define NCHUNK_M (NKEYS / KCHUNK)  // 125
#define LISTM 10

// Monotone (dist, idx) -> u64; dist may be negative (q2 dropped).
__device__ inline unsigned long long enc_key(float d, int n) {
  unsigned u = __float_as_uint(d);
  u ^= (unsigned)((int)u >> 31) | 0x80000000u;
  return ((unsigned long long)u << 32) | (unsigned)n;
}

__device__ inline unsigned long long wave_min_u64(unsigned long long w) {
#pragma unroll
  for (int off = 1; off < 64; off <<= 1) {
    unsigned long long o =
        (unsigned long long)__shfl_xor((long long)w, off, 64);
    if (o < w) w = o;
  }
  return w;
}

__device__ inline void insert10(unsigned long long best[LISTM],
                                unsigned long long key) {
  if (key < best[LISTM - 1]) {
    best[LISTM - 1] = key;
#pragma unroll
    for (int s = LISTM - 1; s >= 1; --s) {
      if (best[s] < best[s - 1]) {
        unsigned long long t = best[s];
        best[s] = best[s - 1];
        best[s - 1] = t;
      }
    }
  }
}

// ---------------------------------------------------------------------------
// Kernel 1 (R11): FUSED prep + MFMA part. One wave per (16-query tile,
// 80-key chunk); reads fp32 q/k directly, converts to split-fp16 hi/lo IN
// REGISTERS (same operand bytes as the former f16 planes -> same traffic),
// computes exact fp32 k2 in-wave:
//   lane's A fragment covers 32 of row (lane&15)'s 128 elems across kc;
//   the 4 lanes sharing lq cover the full row -> shfl_xor(16,32) tree sum,
//   then 4 __shfl to redistribute to the D-layout rows (lane>>4)*4+reg.
// Split-fp16 3-MFMA dot (m89 layout, HW-verified in R10):
//   d = k2 - 2*(Ah*Bh + Ah*Bl + Al*Bh); ll term < 1e-4, dropped.
// No LDS, no barriers, no pre-kernels. 2000 single-wave blocks.
// ---------------------------------------------------------------------------
__global__ __launch_bounds__(64) void knn_part_fused(
    const float* __restrict__ q, const float* __restrict__ k,
    unsigned long long* __restrict__ part) {
  const int qt   = blockIdx.x;   // 0..15
  const int ch   = blockIdx.y;   // 0..124
  const int lane = threadIdx.x;  // 0..63
  const int lq   = lane & 15;
  const int lk8  = (lane >> 4) * 8;
  const int q0   = qt * QTILE;

  // B fragments (queries) once per block: load fp32, convert hi/lo in-reg.
  f16x8 bh[4], bl[4];
  {
    const float* qrow = q + (size_t)(q0 + lq) * DDIM + lk8;
#pragma unroll
    for (int kc = 0; kc < 4; ++kc) {
      f4v v0 = *(const f4v*)(qrow + kc * 32);
      f4v v1 = *(const f4v*)(qrow + kc * 32 + 4);
      float e[8] = {v0.x, v0.y, v0.z, v0.w, v1.x, v1.y, v1.z, v1.w};
#pragma unroll
      for (int j = 0; j < 8; ++j) {
        _Float16 h = (_Float16)e[j];
        bh[kc][j]  = h;
        bl[kc][j]  = (_Float16)(e[j] - (float)h);
      }
    }
  }

  unsigned long long list[LISTM];
#pragma unroll
  for (int s = 0; s < LISTM; ++s) list[s] = ~0ULL;

  const int kbase = ch * KCHUNK;
#pragma unroll 1
  for (int t = 0; t < NTILES; ++t) {
    const int tb = kbase + t * 16;  // tile base key (chunks divide exactly)
    const float* arow = k + (size_t)(tb + lq) * DDIM + lk8;

    f32x4 acc = {0.f, 0.f, 0.f, 0.f};
    float k2p = 0.f;
#pragma unroll
    for (int kc = 0; kc < 4; ++kc) {
      f4v a0 = *(const f4v*)(arow + kc * 32);
      f4v a1 = *(const f4v*)(arow + kc * 32 + 4);
      float e[8] = {a0.x, a0.y, a0.z, a0.w, a1.x, a1.y, a1.z, a1.w};
      f16x8 ah, al;
#pragma unroll
      for (int j = 0; j < 8; ++j) {
        _Float16 h = (_Float16)e[j];
        ah[j]      = h;
        al[j]      = (_Float16)(e[j] - (float)h);
        k2p        = fmaf(e[j], e[j], k2p);  // exact fp32 from fp32 data
      }
      acc = __builtin_amdgcn_mfma_f32_16x16x32_f16(ah, bh[kc], acc, 0, 0, 0);
      acc = __builtin_amdgcn_mfma_f32_16x16x32_f16(ah, bl[kc], acc, 0, 0, 0);
      acc = __builtin_amdgcn_mfma_f32_16x16x32_f16(al, bh[kc], acc, 0, 0, 0);
    }

    // Full ||row(tb+lq)||^2: 4-lane tree over the lq-sharing group.
    k2p += __shfl_xor(k2p, 16, 64);
    k2p += __shfl_xor(k2p, 32, 64);
    // Redistribute to D-layout rows: lane needs rows tb + (lane>>4)*4 + reg;
    // row tb+j is held by lane j (0..15 all have lq=j).
    const int rb = (lane >> 4) * 4;
    const int r0 = tb + rb;
#pragma unroll
    for (int reg = 0; reg < 4; ++reg) {
      float k2v = __shfl(k2p, rb + reg, 64);
      insert10(list, enc_key(fmaf(-2.f, acc[reg], k2v), r0 + reg));
    }
  }

  // Tombstone-extract top-10 across the 4 lanes sharing query lq.
  unsigned long long* dst =
      part + ((size_t)(q0 + lq) * NCHUNK_M + ch) * KSEL;
#pragma unroll 1
  for (int r = 0; r < KSEL; ++r) {
    unsigned long long w = list[0];
    {
      unsigned long long o =
          (unsigned long long)__shfl_xor((long long)w, 16, 64);
      if (o < w) w = o;
      o = (unsigned long long)__shfl_xor((long long)w, 32, 64);
      if (o < w) w = o;
    }
    if (list[0] == w) {
#pragma unroll
      for (int s = 0; s < LISTM - 1; ++s) list[s] = list[s + 1];
      list[LISTM - 1] = ~0ULL;
    }
    if (lane < 16) dst[r] = w;
  }
}

// ---------------------------------------------------------------------------
// Kernel 2: fused merge + gather (R5-proven: cached loads + NT stores,
// barrier-free redundant per-wave merge, scalar copy base).
// ---------------------------------------------------------------------------
template <int NCHUNK_T>
__global__ __launch_bounds__(256) void knn_merge_gather_kernel(
    const float* __restrict__ obs, const unsigned long long* __restrict__ part,
    float* __restrict__ out) {
  constexpr int NCAND_T = NCHUNK_T * KSEL;
  constexpr int SLOTS   = (NCAND_T + 63) / 64;

  const int b    = blockIdx.x;  // b = r*QCNT + q
  const int r    = b >> 8;
  const int qq   = b & 255;
  const int tid  = threadIdx.x;
  const int lane = tid & 63;

  const unsigned long long* cp = part + (size_t)qq * NCAND_T;
  unsigned long long c[SLOTS];
#pragma unroll
  for (int i = 0; i < SLOTS; ++i) {
    const int idx = lane + 64 * i;
    c[i] = (idx < NCAND_T) ? cp[idx] : ~0ULL;
  }
  unsigned long long w = ~0ULL;
#pragma unroll 1
  for (int round = 0; round <= r; ++round) {
    unsigned long long m = c[0];
#pragma unroll
    for (int i = 1; i < SLOTS; ++i) m = (c[i] < m) ? c[i] : m;
    w = wave_min_u64(m);
#pragma unroll
    for (int i = 0; i < SLOTS; ++i)
      if (c[i] == w) c[i] = ~0ULL;
  }
  const int src = __builtin_amdgcn_readfirstlane((int)(w & 0xffffffffu));

  const f4v* __restrict__ s = (const f4v*)(obs + (size_t)src * OBSROW);
  f4v* __restrict__ d       = (f4v*)(out + (size_t)b * OBSROW);
#pragma unroll 4
  for (int i = tid; i < OBSROW / 4; i += 256) {
    f4v v = s[i];  // cached load: L3 catches duplicate rows
    __builtin_nontemporal_store(v, &d[i]);
  }
}

extern "C" void kernel_launch(void* const* d_in, const int* in_sizes, int n_in,
                              void* d_out, int out_size, void* d_ws,
                              size_t ws_size, hipStream_t stream) {
  const float* q   = (const float*)d_in[0];  // [256,128]
  const float* k   = (const float*)d_in[1];  // [10000,128]
  const float* obs = (const float*)d_in[2];  // [10000,4,84,84]
  float* out = (float*)d_out;                // [10,256,4,84,84]

  // ws: part buffer only — 256 * 125 * 10 * 8 = 2,560,000 B (R10 ran the
  // 7.85 MB layout, so ws_size is comfortably sufficient).
  unsigned long long* part = (unsigned long long*)d_ws;

  knn_part_fused<<<dim3(QCNT / QTILE, NCHUNK_M), 64, 0, stream>>>(q, k, part);
  knn_merge_gather_kernel<NCHUNK_M>
      <<<KSEL * QCNT, 256, 0, stream>>>(obs, part, out);
}

// Round 12
// 117.316 us; speedup vs baseline: 1.3020x; 1.0085x over previous
//
#include <hip/hip_runtime.h>
#include <stdint.h>

#define QCNT 256
#define NKEYS 10000
#define DDIM 128
#define KSEL 10
#define OBSROW 28224  // 4*84*84

typedef float f4v __attribute__((ext_vector_type(4)));
typedef float f32x4 __attribute__((ext_vector_type(4)));
typedef _Float16 f16x8 __attribute__((ext_vector_type(8)));

// ---------------- MFMA path geometry ----------------
#define QTILE 16                              // queries per block (MFMA N)
#define KCHUNK 48                             // keys per chunk (3 MFMA tiles)
#define NTILES 3
#define NCHUNK_M ((NKEYS + KCHUNK - 1) / KCHUNK)  // 209 (last: 16 valid keys)
#define LISTM 10

// Monotone (dist, idx) -> u64; dist may be negative (q2 dropped).
__device__ inline unsigned long long enc_key(float d, int n) {
  unsigned u = __float_as_uint(d);
  u ^= (unsigned)((int)u >> 31) | 0x80000000u;
  return ((unsigned long long)u << 32) | (unsigned)n;
}

__device__ inline unsigned long long wave_min_u64(unsigned long long w) {
#pragma unroll
  for (int off = 1; off < 64; off <<= 1) {
    unsigned long long o =
        (unsigned long long)__shfl_xor((long long)w, off, 64);
    if (o < w) w = o;
  }
  return w;
}

__device__ inline void insert10(unsigned long long best[LISTM],
                                unsigned long long key) {
  if (key < best[LISTM - 1]) {
    best[LISTM - 1] = key;
#pragma unroll
    for (int s = LISTM - 1; s >= 1; --s) {
      if (best[s] < best[s - 1]) {
        unsigned long long t = best[s];
        best[s] = best[s - 1];
        best[s - 1] = t;
      }
    }
  }
}

// ---------------------------------------------------------------------------
// Kernel 1 (R12): fused prep + MFMA part, latency-tuned.
//  - KCHUNK 80 -> 48: grid 16x209 = 3344 single-wave blocks (3.3 waves/SIMD,
//    was 2.0) for latency hiding (R11 was latency-bound, not work-bound).
//  - t-loop FULLY unrolled (3 tiles): all 24 dwordx4 key loads can issue
//    before the first MFMA consumes them -> one exposed L2/L3 round trip
//    per chunk instead of three.
// Arithmetic identical to R11 (split-fp16 3-MFMA, in-register hi/lo convert,
// in-wave exact fp32 k2 via 4-lane shfl tree; m89 D-layout).
// Tail chunk (kbase=9984): loads clamped to row NKEYS-1, inserts guarded by
// n < NKEYS; 16 valid keys >= KSEL so all 10 winners remain valid.
// ---------------------------------------------------------------------------
__global__ __launch_bounds__(64) void knn_part_fused(
    const float* __restrict__ q, const float* __restrict__ k,
    unsigned long long* __restrict__ part) {
  const int qt   = blockIdx.x;   // 0..15
  const int ch   = blockIdx.y;   // 0..208
  const int lane = threadIdx.x;  // 0..63
  const int lq   = lane & 15;
  const int lk8  = (lane >> 4) * 8;
  const int q0   = qt * QTILE;

  // B fragments (queries) once per block: load fp32, convert hi/lo in-reg.
  f16x8 bh[4], bl[4];
  {
    const float* qrow = q + (size_t)(q0 + lq) * DDIM + lk8;
#pragma unroll
    for (int kc = 0; kc < 4; ++kc) {
      f4v v0 = *(const f4v*)(qrow + kc * 32);
      f4v v1 = *(const f4v*)(qrow + kc * 32 + 4);
      float e[8] = {v0.x, v0.y, v0.z, v0.w, v1.x, v1.y, v1.z, v1.w};
#pragma unroll
      for (int j = 0; j < 8; ++j) {
        _Float16 h = (_Float16)e[j];
        bh[kc][j]  = h;
        bl[kc][j]  = (_Float16)(e[j] - (float)h);
      }
    }
  }

  unsigned long long list[LISTM];
#pragma unroll
  for (int s = 0; s < LISTM; ++s) list[s] = ~0ULL;

  const int kbase = ch * KCHUNK;
#pragma unroll
  for (int t = 0; t < NTILES; ++t) {
    const int tb  = kbase + t * 16;
    int row       = tb + lq;
    if (row > NKEYS - 1) row = NKEYS - 1;  // clamp (tail chunk only)
    const float* arow = k + (size_t)row * DDIM + lk8;

    f32x4 acc = {0.f, 0.f, 0.f, 0.f};
    float k2p = 0.f;
#pragma unroll
    for (int kc = 0; kc < 4; ++kc) {
      f4v a0 = *(const f4v*)(arow + kc * 32);
      f4v a1 = *(const f4v*)(arow + kc * 32 + 4);
      float e[8] = {a0.x, a0.y, a0.z, a0.w, a1.x, a1.y, a1.z, a1.w};
      f16x8 ah, al;
#pragma unroll
      for (int j = 0; j < 8; ++j) {
        _Float16 h = (_Float16)e[j];
        ah[j]      = h;
        al[j]      = (_Float16)(e[j] - (float)h);
        k2p        = fmaf(e[j], e[j], k2p);  // exact fp32 from fp32 data
      }
      acc = __builtin_amdgcn_mfma_f32_16x16x32_f16(ah, bh[kc], acc, 0, 0, 0);
      acc = __builtin_amdgcn_mfma_f32_16x16x32_f16(ah, bl[kc], acc, 0, 0, 0);
      acc = __builtin_amdgcn_mfma_f32_16x16x32_f16(al, bh[kc], acc, 0, 0, 0);
    }

    // Full ||row||^2: 4-lane tree over the lq-sharing group, then
    // redistribute to the D-layout rows (lane>>4)*4 + reg (row tb+j is
    // held by the 4 lanes with lq == j; lane j is one of them).
    k2p += __shfl_xor(k2p, 16, 64);
    k2p += __shfl_xor(k2p, 32, 64);
    const int rb = (lane >> 4) * 4;
    const int r0 = tb + rb;
#pragma unroll
    for (int reg = 0; reg < 4; ++reg) {
      float k2v = __shfl(k2p, rb + reg, 64);
      const int n = r0 + reg;
      if (n < NKEYS) {
        insert10(list, enc_key(fmaf(-2.f, acc[reg], k2v), n));
      }
    }
  }

  // Tombstone-extract top-10 across the 4 lanes sharing query lq.
  unsigned long long* dst =
      part + ((size_t)(q0 + lq) * NCHUNK_M + ch) * KSEL;
#pragma unroll 1
  for (int r = 0; r < KSEL; ++r) {
    unsigned long long w = list[0];
    {
      unsigned long long o =
          (unsigned long long)__shfl_xor((long long)w, 16, 64);
      if (o < w) w = o;
      o = (unsigned long long)__shfl_xor((long long)w, 32, 64);
      if (o < w) w = o;
    }
    if (list[0] == w) {
#pragma unroll
      for (int s = 0; s < LISTM - 1; ++s) list[s] = list[s + 1];
      list[LISTM - 1] = ~0ULL;
    }
    if (lane < 16) dst[r] = w;
  }
}

// ---------------------------------------------------------------------------
// Kernel 2: fused merge + gather. At SLOTS=33 the 4x-redundant per-wave
// merge would quadruple part-buffer reads, so: wave 0 merges (R3-proven
// structure), one __syncthreads, LDS-broadcast src, then the proven copy
// (cached loads + NT stores).
// ---------------------------------------------------------------------------
template <int NCHUNK_T>
__global__ __launch_bounds__(256) void knn_merge_gather_kernel(
    const float* __restrict__ obs, const unsigned long long* __restrict__ part,
    float* __restrict__ out) {
  constexpr int NCAND_T = NCHUNK_T * KSEL;
  constexpr int SLOTS   = (NCAND_T + 63) / 64;

  const int b    = blockIdx.x;  // b = r*QCNT + q
  const int r    = b >> 8;
  const int qq   = b & 255;
  const int tid  = threadIdx.x;

  __shared__ int s_src;

  if (tid < 64) {
    const unsigned long long* cp = part + (size_t)qq * NCAND_T;
    unsigned long long c[SLOTS];
#pragma unroll
    for (int i = 0; i < SLOTS; ++i) {
      const int idx = tid + 64 * i;
      c[i] = (idx < NCAND_T) ? cp[idx] : ~0ULL;
    }
    unsigned long long w = ~0ULL;
#pragma unroll 1
    for (int round = 0; round <= r; ++round) {
      unsigned long long m = c[0];
#pragma unroll
      for (int i = 1; i < SLOTS; ++i) m = (c[i] < m) ? c[i] : m;
      w = wave_min_u64(m);
#pragma unroll
      for (int i = 0; i < SLOTS; ++i)
        if (c[i] == w) c[i] = ~0ULL;
    }
    if (tid == 0) s_src = (int)(w & 0xffffffffu);
  }
  __syncthreads();
  const int src = __builtin_amdgcn_readfirstlane(s_src);

  const f4v* __restrict__ s = (const f4v*)(obs + (size_t)src * OBSROW);
  f4v* __restrict__ d       = (f4v*)(out + (size_t)b * OBSROW);
#pragma unroll 4
  for (int i = tid; i < OBSROW / 4; i += 256) {
    f4v v = s[i];  // cached load: L3 catches duplicate rows
    __builtin_nontemporal_store(v, &d[i]);
  }
}

extern "C" void kernel_launch(void* const* d_in, const int* in_sizes, int n_in,
                              void* d_out, int out_size, void* d_ws,
                              size_t ws_size, hipStream_t stream) {
  const float* q   = (const float*)d_in[0];  // [256,128]
  const float* k   = (const float*)d_in[1];  // [10000,128]
  const float* obs = (const float*)d_in[2];  // [10000,4,84,84]
  float* out = (float*)d_out;                // [10,256,4,84,84]

  // ws: part buffer = 256 * 209 * 10 * 8 = 4,279,040 B (R10 ran a 7.85 MB
  // layout successfully, so ws_size is sufficient).
  unsigned long long* part = (unsigned long long*)d_ws;

  knn_part_fused<<<dim3(QCNT / QTILE, NCHUNK_M), 64, 0, stream>>>(q, k, part);
  knn_merge_gather_kernel<NCHUNK_M>
      <<<KSEL * QCNT, 256, 0, stream>>>(obs, part, out);
}